// Round 2
// baseline (227.839 us; speedup 1.0000x reference)
//
#include <hip/hip_runtime.h>
#include <stdint.h>

// ListwiseLoss: B=524288 rows, H=32. One THREAD per row, coalesced global
// reads via per-wave LDS staging (16-bit converted staging, round 8).
//   kl_row = sum_valid e_i*(s_i - g_i) / se,  e = exp(s),
//   g_i = s of the (rank_i)-th valid element in index order
// (max-sub and log(se) cancel between the KL sums; eps dropped — validated
//  rounds 1-8, absmax 0.0).
//
// Round-9: SOFTWARE PIPELINE across tiles (latency attack). Evidence from
// round 8: cache-warm dispatches (hbm_bytes~0.13MB) ran at the SAME 87us as
// HBM-fed ones -> pure latency-bound; occupancy pinned at ~12 waves/CU
// regardless of LDS size -> more resident waves unobtainable. Fix: each wave
// processes NT=2 tiles of 64 rows; global loads for tile t+1 are issued into
// registers while tile t runs its LDS round trips + SWAR compute (~4000 cyc),
// hiding the ~900-cycle load latency in-wave. Prefetch issue points:
// ranks+mask right after phase A consumes their regs, scores right after
// phase B. LDS single-buffered per wave (same-wave DS ops are in-order, so
// tile t+1's staging writes queue behind tile t's gather reads; no barriers).
// Grid 1024 blocks x 4 waves x 2 tiles = 4096 waves, ALL resident (16/CU).
// __launch_bounds__(256,4) caps VGPR at ~128 to keep 4 waves/SIMD.
//
// Staging (round 8): staged key16 = valid ? (r<<5) : 0x4000 (reader ORs in
// element idx); scores staged as bf16 pairs. Row = 16 data dwords + 1 pad
// (odd stride -> bank-rotated, conflict-free). Gather row overlays score row;
// park slot = u16 33. 32x32 rank count = packed-i16 SWAR.

#define H 32
#define BLK 256
#define WPB 4
#define NT 2                  // tiles (of 64 rows) per wave, software-pipelined
#define ROWD 17               // dwords per staged row (16 data + 1 pad)
#define WREGION (64 * ROWD)   // 1088 dwords = 4352 B per wave

typedef short s16x2 __attribute__((ext_vector_type(2)));
union PK { uint32_t u; s16x2 v; };

__global__ __launch_bounds__(BLK, 4) void listwise_kernel(
    const float* __restrict__ scores,
    const int* __restrict__ rankings,
    const unsigned char* __restrict__ mask_u8,
    float* __restrict__ part_kl,
    float* __restrict__ part_cnt,
    int nrows)
{
    __shared__ uint32_t stage[WPB * WREGION];   // 17408 B
    __shared__ float s_kl[WPB], s_cnt[WPB];

    const int tid  = threadIdx.x;
    const int lane = tid & 63;
    const int wid  = tid >> 6;
    uint32_t* wbuf = &stage[wid * WREGION];
    const int wave_g   = blockIdx.x * WPB + wid;
    const int row_base = wave_g * (NT * 64);

    // ---- tile-0 prefetch: issue BEFORE the mask-dtype probe round trip ----
    uint4 pr[8], ps[8];       // next-tile rank / score prefetch registers
    uint32_t pmw[8];          // next-tile mask dwords (bool path)
    const bool t0_full = (row_base + 64 <= nrows);
    if (t0_full) {
        const uint4* r4 = (const uint4*)(rankings + (size_t)row_base * H);
        const uint4* s4 = (const uint4*)(scores + (size_t)row_base * H);
        #pragma unroll
        for (int c = 0; c < 8; ++c) pr[c] = r4[lane + 64 * c];
        #pragma unroll
        for (int c = 0; c < 8; ++c) ps[c] = s4[lane + 64 * c];
    }

    // mask dtype detect (bool=1B vs int32=4B); wave-uniform branch
    unsigned char probe = mask_u8[lane];
    const bool mask_is_i32 =
        (__ballot(((lane & 3) != 0) && (probe != 0)) == 0ull);
    if (t0_full && !mask_is_i32) {
        const uint32_t* m1 = (const uint32_t*)(mask_u8 + (size_t)row_base * H);
        #pragma unroll
        for (int c = 0; c < 8; ++c) pmw[c] = m1[lane + 64 * c];
    }

    float kl = 0.0f, cnt = 0.0f;
    unsigned short* rowp = (unsigned short*)&wbuf[lane * ROWD];

    #pragma unroll
    for (int t = 0; t < NT; ++t) {
        const int wrow0 = row_base + t * 64;
        uint32_t kp[16], sp[16];
        int nv = 0;
        bool have = false;

        if (wrow0 + 64 <= nrows) {
            have = true;

            // ===== phase A: ranks+mask -> staged u16 key (sans idx) =====
            if (!mask_is_i32) {
                #pragma unroll
                for (int c = 0; c < 8; ++c) {
                    const uint4 rv = pr[c];
                    const uint32_t mv = pmw[c];
                    const int L = (lane + 64 * c) << 2;   // elem idx 0..2047
                    const uint32_t t0 = ((mv & 0x000000FFu) != 0u && (int)rv.x > 0) ? (rv.x << 5) : 0x4000u;
                    const uint32_t t1 = ((mv & 0x0000FF00u) != 0u && (int)rv.y > 0) ? (rv.y << 5) : 0x4000u;
                    const uint32_t t2 = ((mv & 0x00FF0000u) != 0u && (int)rv.z > 0) ? (rv.z << 5) : 0x4000u;
                    const uint32_t t3 = ((mv & 0xFF000000u) != 0u && (int)rv.w > 0) ? (rv.w << 5) : 0x4000u;
                    uint32_t* d = &wbuf[(L >> 5) * ROWD + ((L & 31) >> 1)];
                    d[0] = t0 | (t1 << 16);
                    d[1] = t2 | (t3 << 16);
                }
            } else {
                // i32-mask path: mask loaded in-phase (not the bench dtype;
                // keeps register pressure off the hot path)
                const uint4* m4 =
                    (const uint4*)((const uint32_t*)mask_u8 + (size_t)wrow0 * H);
                #pragma unroll
                for (int c = 0; c < 8; ++c) {
                    const uint4 rv = pr[c];
                    const uint4 mv = m4[lane + 64 * c];
                    const int L = (lane + 64 * c) << 2;
                    const uint32_t t0 = (mv.x != 0u && (int)rv.x > 0) ? (rv.x << 5) : 0x4000u;
                    const uint32_t t1 = (mv.y != 0u && (int)rv.y > 0) ? (rv.y << 5) : 0x4000u;
                    const uint32_t t2 = (mv.z != 0u && (int)rv.z > 0) ? (rv.z << 5) : 0x4000u;
                    const uint32_t t3 = (mv.w != 0u && (int)rv.w > 0) ? (rv.w << 5) : 0x4000u;
                    uint32_t* d = &wbuf[(L >> 5) * ROWD + ((L & 31) >> 1)];
                    d[0] = t0 | (t1 << 16);
                    d[1] = t2 | (t3 << 16);
                }
            }

            // ---- prefetch next tile's ranks+mask (pr/pmw just freed) ----
            if (t + 1 < NT) {
                const int nr0 = row_base + (t + 1) * 64;
                if (nr0 + 64 <= nrows) {
                    const uint4* r4n = (const uint4*)(rankings + (size_t)nr0 * H);
                    #pragma unroll
                    for (int c = 0; c < 8; ++c) pr[c] = r4n[lane + 64 * c];
                    if (!mask_is_i32) {
                        const uint32_t* m1n =
                            (const uint32_t*)(mask_u8 + (size_t)nr0 * H);
                        #pragma unroll
                        for (int c = 0; c < 8; ++c) pmw[c] = m1n[lane + 64 * c];
                    }
                }
            }

            // ---- readback own row: packed keys + valid count (bit14 SWAR)
            {
                const uint32_t* rb = &wbuf[lane * ROWD];
                uint32_t inv2 = 0;
                #pragma unroll
                for (int a = 0; a < 16; ++a) {
                    const uint32_t w = rb[a];
                    kp[a] = w | ((uint32_t)(2 * a) | (((uint32_t)(2 * a + 1)) << 16));
                    inv2 += (w >> 14) & 0x00010001u;   // invalid flag per half
                }
                nv = 32 - (int)((inv2 & 0xFFFFu) + (inv2 >> 16));
            }

            // ===== phase B: scores -> staged bf16 pairs =====
            #pragma unroll
            for (int c = 0; c < 8; ++c) {
                const uint4 v = ps[c];
                const int L = (lane + 64 * c) << 2;
                const uint32_t b0 = (v.x + 0x8000u) >> 16;   // bf16 rnd
                const uint32_t b1 = (v.y + 0x8000u) >> 16;
                const uint32_t b2 = (v.z + 0x8000u) >> 16;
                const uint32_t b3 = (v.w + 0x8000u) >> 16;
                uint32_t* d = &wbuf[(L >> 5) * ROWD + ((L & 31) >> 1)];
                d[0] = b0 | (b1 << 16);
                d[1] = b2 | (b3 << 16);
            }

            // ---- prefetch next tile's scores (ps just freed) ----
            if (t + 1 < NT) {
                const int nr0 = row_base + (t + 1) * 64;
                if (nr0 + 64 <= nrows) {
                    const uint4* s4n = (const uint4*)(scores + (size_t)nr0 * H);
                    #pragma unroll
                    for (int c = 0; c < 8; ++c) ps[c] = s4n[lane + 64 * c];
                }
            }

            // ---- readback scores + gather-row compaction ----
            {
                const uint32_t* rb = &wbuf[lane * ROWD];
                int jp = 0;
                #pragma unroll
                for (int a = 0; a < 16; ++a) {
                    const uint32_t sw = rb[a];
                    sp[a] = sw;
                    const uint32_t kw = kp[a];
                    const bool v0 = (kw & 0xFFFFu) < 0x4000u;
                    const bool v1 = (kw >> 16) < 0x4000u;
                    rowp[v0 ? jp : 33] = (unsigned short)(sw & 0xFFFFu); // park->33
                    jp += v0 ? 1 : 0;
                    rowp[v1 ? jp : 33] = (unsigned short)(sw >> 16);
                    jp += v1 ? 1 : 0;
                }
            }
        } else if (wrow0 + lane < nrows) {
            // ---- tail (never hit at B=524288): per-thread scalar path
            have = true;
            const int row = wrow0 + lane;
            const int*   rptr = rankings + (size_t)row * H;
            const float* sptr = scores + (size_t)row * H;
            uint32_t vbits = 0;
            if (mask_is_i32) {
                const int* mp = (const int*)mask_u8 + (size_t)row * H;
                #pragma unroll
                for (int k = 0; k < H; ++k) vbits |= (mp[k] != 0 ? 1u : 0u) << k;
            } else {
                const unsigned char* mp = mask_u8 + (size_t)row * H;
                #pragma unroll
                for (int k = 0; k < H; ++k) vbits |= (mp[k] != 0 ? 1u : 0u) << k;
            }
            int jp = 0;
            #pragma unroll
            for (int a = 0; a < 16; ++a) {
                uint32_t kq[2], bq[2];
                #pragma unroll
                for (int q = 0; q < 2; ++q) {
                    const int k = 2 * a + q;
                    const int r = rptr[k];
                    const bool valid = (((vbits >> k) & 1u) != 0u) && (r > 0);
                    kq[q] = valid ? ((((uint32_t)r) << 5) | (uint32_t)k)
                                  : (0x4000u | (uint32_t)k);
                    nv += valid ? 1 : 0;
                    bq[q] = (__float_as_uint(sptr[k]) + 0x8000u) >> 16;
                    rowp[valid ? jp : 33] = (unsigned short)bq[q];
                    jp += valid ? 1 : 0;
                }
                kp[a] = kq[0] | (kq[1] << 16);
                sp[a] = bq[0] | (bq[1] << 16);
            }
        }

        if (have) {
            // ===== phase C: SWAR rank-count, gather, accumulate =====
            float se = 0.0f, num = 0.0f;
            #pragma unroll
            for (int i = 0; i < H; ++i) {
                const uint32_t pw = kp[i / 2];
                const uint32_t k16 = (i & 1) ? (pw >> 16) : (pw & 0xFFFFu);
                PK b; b.u = (k16 << 16) | k16;
                PK acc; acc.u = 0;
                #pragma unroll
                for (int m = 0; m < 16; ++m) {
                    PK pm_; pm_.u = kp[m];
                    s16x2 d = pm_.v - b.v;           // v_pk_sub_i16
                    acc.v = acc.v - (d >> 15);       // +1 per (key_m < key_i)
                }
                const int j = (int)acc.v.x + (int)acc.v.y;   // rank 0..31
                const float g = __uint_as_float(((uint32_t)rowp[j]) << 16);
                const uint32_t sw = sp[i / 2];
                const float s_i = __uint_as_float((i & 1) ? (sw & 0xFFFF0000u)
                                                          : (sw << 16));
                const bool valid = k16 < 0x4000u;
                float e = __expf(s_i);
                e = valid ? e : 0.0f;
                const float d2 = valid ? (s_i - g) : 0.0f;
                se += e;
                num = __builtin_fmaf(e, d2, num);
            }
            if (nv > 1) { kl += __fdividef(num, se); cnt += 1.0f; }
        }
    }

    // ---- block reduction; unconditional partial write (no memset/atomics)
    #pragma unroll
    for (int m = 32; m >= 1; m >>= 1) {
        kl  += __shfl_xor(kl, m);
        cnt += __shfl_xor(cnt, m);
    }
    if (lane == 0) { s_kl[wid] = kl; s_cnt[wid] = cnt; }
    __syncthreads();
    if (tid == 0) {
        part_kl[blockIdx.x]  = s_kl[0] + s_kl[1] + s_kl[2] + s_kl[3];
        part_cnt[blockIdx.x] = s_cnt[0] + s_cnt[1] + s_cnt[2] + s_cnt[3];
    }
}

__global__ __launch_bounds__(256) void finalize_kernel(
    const float* __restrict__ part_kl,
    const float* __restrict__ part_cnt,
    float* __restrict__ out, int nblk)
{
    float k = 0.0f, c = 0.0f;
    for (int i = threadIdx.x; i < nblk; i += 256) {
        k += part_kl[i];
        c += part_cnt[i];
    }
    #pragma unroll
    for (int m = 32; m >= 1; m >>= 1) {
        k += __shfl_xor(k, m);
        c += __shfl_xor(c, m);
    }
    __shared__ float sk[4], sc[4];
    const int wid = threadIdx.x >> 6;
    if ((threadIdx.x & 63) == 0) { sk[wid] = k; sc[wid] = c; }
    __syncthreads();
    if (threadIdx.x == 0) {
        float K = sk[0] + sk[1] + sk[2] + sk[3];
        float C = sc[0] + sc[1] + sc[2] + sc[3];
        if (C < 1.0f) C = 1.0f;
        out[0] = K / C;
    }
}

extern "C" void kernel_launch(void* const* d_in, const int* in_sizes, int n_in,
                              void* d_out, int out_size, void* d_ws, size_t ws_size,
                              hipStream_t stream) {
    const float* scores = (const float*)d_in[0];
    const int* rankings = (const int*)d_in[1];
    const unsigned char* mask = (const unsigned char*)d_in[2];
    float* out = (float*)d_out;

    const int total = in_sizes[0];       // B*H = 16777216
    const int nrows = total / H;         // 524288 rows
    const int rows_per_block = WPB * NT * 64;            // 512
    const int blocks = (nrows + rows_per_block - 1) / rows_per_block;  // 1024

    float* part_kl  = (float*)d_ws;               // [0, blocks)
    float* part_cnt = (float*)d_ws + blocks;      // [blocks, 2*blocks)

    listwise_kernel<<<blocks, BLK, 0, stream>>>(
        scores, rankings, mask, part_kl, part_cnt, nrows);

    finalize_kernel<<<1, 256, 0, stream>>>(part_kl, part_cnt, out, blocks);
}

// Round 3
// 199.654 us; speedup vs baseline: 1.1412x; 1.1412x over previous
//
#include <hip/hip_runtime.h>
#include <stdint.h>

// ListwiseLoss: B=524288 rows, H=32. One THREAD per row, coalesced global
// reads via per-wave LDS staging (16-bit converted staging, round 8).
//   kl_row = sum_valid e_i*(s_i - g_i) / se,  e = exp(s),
//   g_i = s of the (rank_i)-th valid element in index order
// (max-sub and log(se) cancel between the KL sums; eps dropped — validated
//  rounds 1-9, absmax 0.0).
//
// Round-10: BITONIC SORT replaces the O(H^2) SWAR rank-count (VALU attack).
// Evidence: VALUBusy(36%) x dur == computed VALU-issue work (~30us) -> the
// kernel is VALU-issue-bound; warm==cold dispatch time -> memory irrelevant.
// The SWAR rank-count was 1536 packed ops/thread + a data-dependent LDS
// gather per element. Replacement: pack (key16<<16)|bf16score into 32 u32s
// and bitonic-sort in registers: 240 compare-exchanges = 480 v_min/max_u32,
// all compile-time register indices (no scratch), 16 independent CEs per
// stage (ILP). Valid elements land in rank order with scores attached; the
// comp[] gather becomes CONSTANT-offset ds_reads (mergeable, dependency-free).
// Round-9's register-prefetch pipeline is REVERTED (it spilled: WRITE_SIZE
// 129KB -> 49MB of scratch). Kept from it: all global loads (ranks, scores,
// bool-layout mask) are issued BEFORE the mask-probe ballot so a single
// vmcnt wait covers every global access.
//
// Staging (round 8): staged key16 = valid ? (r<<5) : 0x4000 (reader ORs in
// element idx); scores staged as bf16 pairs. Row = 16 data dwords + 1 pad
// (odd stride -> bank-rotated). Gather row overlays score row; park slot =
// u16 33. Same-wave DS ops are in-order per lane-row: no barriers needed.

#define H 32
#define BLK 256
#define WPB 4
#define ROWD 17               // dwords per staged row (16 data + 1 pad)
#define WREGION (64 * ROWD)   // 1088 dwords = 4352 B per wave

__global__ __launch_bounds__(BLK) void listwise_kernel(
    const float* __restrict__ scores,
    const int* __restrict__ rankings,
    const unsigned char* __restrict__ mask_u8,
    float* __restrict__ part_kl,
    float* __restrict__ part_cnt,
    int nrows)
{
    __shared__ uint32_t stage[WPB * WREGION];   // 17408 B
    __shared__ float s_kl[WPB], s_cnt[WPB];

    const int tid  = threadIdx.x;
    const int lane = tid & 63;
    const int wid  = tid >> 6;
    uint32_t* wbuf = &stage[wid * WREGION];
    const int wrow0 = blockIdx.x * BLK + wid * 64;   // wave's 64 rows

    float kl = 0.0f, cnt = 0.0f;
    uint32_t kp[16], sw[16];
    int nv = 0;
    bool have_row = false;
    unsigned short* rowp = (unsigned short*)&wbuf[lane * ROWD];

    const bool full = (wrow0 + 64 <= nrows);

    // ---- issue ALL global loads before the probe ballot (one vmcnt wait
    //      covers everything). bool-layout mask read is in-bounds even when
    //      the real dtype is i32 (buffer is 4x larger); values unused then.
    uint4 pr[8], ps[8];
    uint32_t pmw[8];
    if (full) {
        const uint4* r4 = (const uint4*)(rankings + (size_t)wrow0 * H);
        const uint4* s4 = (const uint4*)(scores + (size_t)wrow0 * H);
        const uint32_t* m1 = (const uint32_t*)(mask_u8 + (size_t)wrow0 * H);
        #pragma unroll
        for (int c = 0; c < 8; ++c) pr[c] = r4[lane + 64 * c];
        #pragma unroll
        for (int c = 0; c < 8; ++c) ps[c] = s4[lane + 64 * c];
        #pragma unroll
        for (int c = 0; c < 8; ++c) pmw[c] = m1[lane + 64 * c];
    }

    // mask dtype detect (bool=1B vs int32=4B); wave-uniform branch
    unsigned char probe = mask_u8[lane];
    const bool mask_is_i32 =
        (__ballot(((lane & 3) != 0) && (probe != 0)) == 0ull);

    if (full) {
        have_row = true;

        // ===== phase B first (no mask dependency): scores -> bf16 staged ====
        #pragma unroll
        for (int c = 0; c < 8; ++c) {
            const uint4 v = ps[c];
            const int L = (lane + 64 * c) << 2;
            uint32_t* d = &wbuf[(L >> 5) * ROWD + ((L & 31) >> 1)];
            d[0] = ((v.x + 0x8000u) >> 16) | (((v.y + 0x8000u) >> 16) << 16);
            d[1] = ((v.z + 0x8000u) >> 16) | (((v.w + 0x8000u) >> 16) << 16);
        }
        {   // readback own row's scores (same-wave DS in-order)
            const uint32_t* rb = &wbuf[lane * ROWD];
            #pragma unroll
            for (int a = 0; a < 16; ++a) sw[a] = rb[a];
        }

        // ===== phase A: ranks+mask -> staged u16 key (sans idx) =====
        if (!mask_is_i32) {
            #pragma unroll
            for (int c = 0; c < 8; ++c) {
                const uint4 rv = pr[c];
                const uint32_t mv = pmw[c];
                const int L = (lane + 64 * c) << 2;   // elem idx 0..2047
                const uint32_t t0 = ((mv & 0x000000FFu) != 0u && (int)rv.x > 0) ? (rv.x << 5) : 0x4000u;
                const uint32_t t1 = ((mv & 0x0000FF00u) != 0u && (int)rv.y > 0) ? (rv.y << 5) : 0x4000u;
                const uint32_t t2 = ((mv & 0x00FF0000u) != 0u && (int)rv.z > 0) ? (rv.z << 5) : 0x4000u;
                const uint32_t t3 = ((mv & 0xFF000000u) != 0u && (int)rv.w > 0) ? (rv.w << 5) : 0x4000u;
                uint32_t* d = &wbuf[(L >> 5) * ROWD + ((L & 31) >> 1)];
                d[0] = t0 | (t1 << 16);
                d[1] = t2 | (t3 << 16);
            }
        } else {
            // i32-mask path (not the bench dtype): mask loaded in-phase
            const uint4* m4 =
                (const uint4*)((const uint32_t*)mask_u8 + (size_t)wrow0 * H);
            #pragma unroll
            for (int c = 0; c < 8; ++c) {
                const uint4 rv = pr[c];
                const uint4 mv = m4[lane + 64 * c];
                const int L = (lane + 64 * c) << 2;
                const uint32_t t0 = (mv.x != 0u && (int)rv.x > 0) ? (rv.x << 5) : 0x4000u;
                const uint32_t t1 = (mv.y != 0u && (int)rv.y > 0) ? (rv.y << 5) : 0x4000u;
                const uint32_t t2 = (mv.z != 0u && (int)rv.z > 0) ? (rv.z << 5) : 0x4000u;
                const uint32_t t3 = (mv.w != 0u && (int)rv.w > 0) ? (rv.w << 5) : 0x4000u;
                uint32_t* d = &wbuf[(L >> 5) * ROWD + ((L & 31) >> 1)];
                d[0] = t0 | (t1 << 16);
                d[1] = t2 | (t3 << 16);
            }
        }
        {   // readback keys + valid count (bit14 SWAR)
            const uint32_t* rb = &wbuf[lane * ROWD];
            uint32_t inv2 = 0;
            #pragma unroll
            for (int a = 0; a < 16; ++a) {
                const uint32_t w = rb[a];
                kp[a] = w | ((uint32_t)(2 * a) | (((uint32_t)(2 * a + 1)) << 16));
                inv2 += (w >> 14) & 0x00010001u;   // invalid flag per half
            }
            nv = 32 - (int)((inv2 & 0xFFFFu) + (inv2 >> 16));
        }
        {   // gather-row compaction: valid scores in index order
            int jp = 0;
            #pragma unroll
            for (int a = 0; a < 16; ++a) {
                const uint32_t s2 = sw[a];
                const uint32_t kw = kp[a];
                const bool v0 = (kw & 0xFFFFu) < 0x4000u;
                const bool v1 = (kw >> 16) < 0x4000u;
                rowp[v0 ? jp : 33] = (unsigned short)(s2 & 0xFFFFu); // park->33
                jp += v0 ? 1 : 0;
                rowp[v1 ? jp : 33] = (unsigned short)(s2 >> 16);
                jp += v1 ? 1 : 0;
            }
        }
    } else if (wrow0 + lane < nrows) {
        // ---- tail (never hit at B=524288): per-thread scalar path
        have_row = true;
        const int row = wrow0 + lane;
        const int*   rptr = rankings + (size_t)row * H;
        const float* sptr = scores + (size_t)row * H;
        uint32_t vbits = 0;
        if (mask_is_i32) {
            const int* mp = (const int*)mask_u8 + (size_t)row * H;
            #pragma unroll
            for (int k = 0; k < H; ++k) vbits |= (mp[k] != 0 ? 1u : 0u) << k;
        } else {
            const unsigned char* mp = mask_u8 + (size_t)row * H;
            #pragma unroll
            for (int k = 0; k < H; ++k) vbits |= (mp[k] != 0 ? 1u : 0u) << k;
        }
        int jp = 0;
        #pragma unroll
        for (int a = 0; a < 16; ++a) {
            uint32_t kq[2], bq[2];
            #pragma unroll
            for (int q = 0; q < 2; ++q) {
                const int k = 2 * a + q;
                const int r = rptr[k];
                const bool valid = (((vbits >> k) & 1u) != 0u) && (r > 0);
                kq[q] = valid ? ((((uint32_t)r) << 5) | (uint32_t)k)
                              : (0x4000u | (uint32_t)k);
                nv += valid ? 1 : 0;
                bq[q] = (__float_as_uint(sptr[k]) + 0x8000u) >> 16;
                rowp[valid ? jp : 33] = (unsigned short)bq[q];
                jp += valid ? 1 : 0;
            }
            kp[a] = kq[0] | (kq[1] << 16);
            sw[a] = bq[0] | (bq[1] << 16);
        }
    }

    if (have_row) {
        // ===== pack (key16<<16)|bf16 and bitonic-sort 32 words =====
        uint32_t w32[32];
        #pragma unroll
        for (int a = 0; a < 16; ++a) {
            const uint32_t kw = kp[a], s2 = sw[a];
            w32[2 * a]     = (kw << 16) | (s2 & 0xFFFFu);
            w32[2 * a + 1] = (kw & 0xFFFF0000u) | (s2 >> 16);
        }
        // ascending bitonic network, n=32: 15 substages x 16 CEs = 240 CEs,
        // all indices compile-time (registers, no scratch)
        #pragma unroll
        for (int k = 2; k <= 32; k <<= 1) {
            #pragma unroll
            for (int j = k >> 1; j > 0; j >>= 1) {
                #pragma unroll
                for (int i = 0; i < 32; ++i) {
                    const int l = i ^ j;
                    if (l > i) {
                        const uint32_t a = w32[i], b = w32[l];
                        const uint32_t mn = a < b ? a : b;   // v_min_u32
                        const uint32_t mx = a < b ? b : a;   // v_max_u32
                        const bool up = ((i & k) == 0);
                        w32[i] = up ? mn : mx;
                        w32[l] = up ? mx : mn;
                    }
                }
            }
        }

        // ===== final: pair sorted (rank-order) with compacted (index-order)
        //       comp reads are CONSTANT-offset ds_reads (dependency-free) ====
        float se = 0.0f, num = 0.0f;
        const uint32_t* rbd = &wbuf[lane * ROWD];
        #pragma unroll
        for (int a = 0; a < 16; ++a) {
            const uint32_t cw = rbd[a];          // comp[2a], comp[2a+1]
            #pragma unroll
            for (int q = 0; q < 2; ++q) {
                const uint32_t wv = w32[2 * a + q];
                const bool valid = wv < 0x40000000u;       // key16 < 0x4000
                const float s_i = __uint_as_float(wv << 16);
                const uint32_t c16 = q ? (cw >> 16) : (cw & 0xFFFFu);
                const float g = __uint_as_float(c16 << 16);
                float e = __expf(s_i);
                e = valid ? e : 0.0f;
                const float d2 = valid ? (s_i - g) : 0.0f;
                se += e;
                num = __builtin_fmaf(e, d2, num);
            }
        }
        if (nv > 1) { kl = __fdividef(num, se); cnt = 1.0f; }
    }

    // ---- block reduction; unconditional partial write (no memset/atomics)
    #pragma unroll
    for (int m = 32; m >= 1; m >>= 1) {
        kl  += __shfl_xor(kl, m);
        cnt += __shfl_xor(cnt, m);
    }
    if (lane == 0) { s_kl[wid] = kl; s_cnt[wid] = cnt; }
    __syncthreads();
    if (tid == 0) {
        part_kl[blockIdx.x]  = s_kl[0] + s_kl[1] + s_kl[2] + s_kl[3];
        part_cnt[blockIdx.x] = s_cnt[0] + s_cnt[1] + s_cnt[2] + s_cnt[3];
    }
}

__global__ __launch_bounds__(256) void finalize_kernel(
    const float* __restrict__ part_kl,
    const float* __restrict__ part_cnt,
    float* __restrict__ out, int nblk)
{
    float k = 0.0f, c = 0.0f;
    for (int i = threadIdx.x; i < nblk; i += 256) {
        k += part_kl[i];
        c += part_cnt[i];
    }
    #pragma unroll
    for (int m = 32; m >= 1; m >>= 1) {
        k += __shfl_xor(k, m);
        c += __shfl_xor(c, m);
    }
    __shared__ float sk[4], sc[4];
    const int wid = threadIdx.x >> 6;
    if ((threadIdx.x & 63) == 0) { sk[wid] = k; sc[wid] = c; }
    __syncthreads();
    if (threadIdx.x == 0) {
        float K = sk[0] + sk[1] + sk[2] + sk[3];
        float C = sc[0] + sc[1] + sc[2] + sc[3];
        if (C < 1.0f) C = 1.0f;
        out[0] = K / C;
    }
}

extern "C" void kernel_launch(void* const* d_in, const int* in_sizes, int n_in,
                              void* d_out, int out_size, void* d_ws, size_t ws_size,
                              hipStream_t stream) {
    const float* scores = (const float*)d_in[0];
    const int* rankings = (const int*)d_in[1];
    const unsigned char* mask = (const unsigned char*)d_in[2];
    float* out = (float*)d_out;

    const int total = in_sizes[0];       // B*H = 16777216
    const int nrows = total / H;         // 524288 rows
    const int blocks = (nrows + BLK - 1) / BLK;   // 2048

    float* part_kl  = (float*)d_ws;               // [0, blocks)
    float* part_cnt = (float*)d_ws + blocks;      // [blocks, 2*blocks)

    listwise_kernel<<<blocks, BLK, 0, stream>>>(
        scores, rankings, mask, part_kl, part_cnt, nrows);

    finalize_kernel<<<1, 256, 0, stream>>>(part_kl, part_cnt, out, blocks);
}